// Round 3
// baseline (2163.791 us; speedup 1.0000x reference)
//
#include <hip/hip_runtime.h>
#include <hip/hip_bf16.h>

#define NN 100000
#define NE 1600000
#define NF 128
#define NH 64
#define NC 10
#define NG 64

// ---- degree count over dst ----
__global__ void k_deg(const int* __restrict__ dst, int* __restrict__ cnt) {
    int e = blockIdx.x * blockDim.x + threadIdx.x;
    if (e < NE) atomicAdd(&cnt[dst[e]], 1);
}

__global__ void k_dinv(const int* __restrict__ cnt, float* __restrict__ dinv) {
    int i = blockIdx.x * blockDim.x + threadIdx.x;
    if (i < NN) dinv[i] = rsqrtf((float)cnt[i] + 1.0f);  // +1 self-loop
}

// ---- t = h @ W, h f32 [NN,128], W f32 [128,64] ----
__global__ __launch_bounds__(256) void k_gemm_in(const float* __restrict__ h,
                                                 const float* __restrict__ W,
                                                 float* __restrict__ t) {
    __shared__ float w_lds[NF * NH];  // 32 KB
    for (int idx = threadIdx.x; idx < NF * NH; idx += 256)
        w_lds[idx] = W[idx];
    __syncthreads();
    int lane = threadIdx.x & 63;
    int wave = (blockIdx.x * 256 + threadIdx.x) >> 6;
    int nw = (gridDim.x * 256) >> 6;
    for (int n = wave; n < NN; n += nw) {
        const float4* hv = (const float4*)(h + (size_t)n * NF);
        float acc = 0.f;
#pragma unroll
        for (int q = 0; q < NF / 4; q++) {
            float4 v = hv[q];
            int k = q * 4;
            acc = fmaf(v.x, w_lds[(k + 0) * NH + lane], acc);
            acc = fmaf(v.y, w_lds[(k + 1) * NH + lane], acc);
            acc = fmaf(v.z, w_lds[(k + 2) * NH + lane], acc);
            acc = fmaf(v.w, w_lds[(k + 3) * NH + lane], acc);
        }
        t[(size_t)n * NH + lane] = acc;
    }
}

// ---- t = h @ W, h f32 [NN,64], W f32 [64,64] ----
__global__ __launch_bounds__(256) void k_gemm_h(const float* __restrict__ h,
                                                const float* __restrict__ W,
                                                float* __restrict__ t) {
    __shared__ float w_lds[NH * NH];  // 16 KB
    for (int idx = threadIdx.x; idx < NH * NH; idx += 256)
        w_lds[idx] = W[idx];
    __syncthreads();
    int lane = threadIdx.x & 63;
    int wave = (blockIdx.x * 256 + threadIdx.x) >> 6;
    int nw = (gridDim.x * 256) >> 6;
    for (int n = wave; n < NN; n += nw) {
        const float4* hv = (const float4*)(h + (size_t)n * NH);
        float acc = 0.f;
#pragma unroll
        for (int q = 0; q < NH / 4; q++) {
            float4 v = hv[q];
            int k = q * 4;
            acc = fmaf(v.x, w_lds[(k + 0) * NH + lane], acc);
            acc = fmaf(v.y, w_lds[(k + 1) * NH + lane], acc);
            acc = fmaf(v.z, w_lds[(k + 2) * NH + lane], acc);
            acc = fmaf(v.w, w_lds[(k + 3) * NH + lane], acc);
        }
        t[(size_t)n * NH + lane] = acc;
    }
}

// ---- edge scatter: one wave per edge, lane = feature ----
__global__ __launch_bounds__(256) void k_agg(const int* __restrict__ ei,
                                             const float* __restrict__ dinv,
                                             const float* __restrict__ t,
                                             float* __restrict__ agg) {
    int wave = (blockIdx.x * 256 + threadIdx.x) >> 6;
    int lane = threadIdx.x & 63;
    if (wave >= NE) return;
    int s = ei[wave];
    int d = ei[NE + wave];
    float nrm = dinv[s] * dinv[d];
    float v = t[(size_t)s * NH + lane] * nrm;
    atomicAdd(&agg[(size_t)d * NH + lane], v);
}

// ---- epilogue: x = relu(agg + t*dinv^2 + b); re-zero agg for next layer ----
__global__ __launch_bounds__(256) void k_epi(float* __restrict__ agg,
                                             const float* __restrict__ t,
                                             const float* __restrict__ dinv,
                                             const float* __restrict__ b,
                                             float* __restrict__ xout) {
    size_t i = (size_t)blockIdx.x * 256 + threadIdx.x;
    if (i >= (size_t)NN * NH) return;
    int n = (int)(i >> 6);
    int j = (int)(i & 63);
    float di = dinv[n];
    float val = agg[i] + t[i] * di * di + b[j];
    agg[i] = 0.f;
    xout[i] = fmaxf(val, 0.f);
}

// ---- mean-pool slice (batch sorted): block walks NB nodes, flush per segment ----
__global__ __launch_bounds__(64) void k_pool(const float* __restrict__ src,
                                             const int* __restrict__ batch,
                                             float* __restrict__ pooled,
                                             float* __restrict__ gcnt,
                                             int sliceoff, int do_gcnt) {
    const int NB = 128;
    int j = threadIdx.x;  // 0..63
    int n0 = blockIdx.x * NB;
    int nend = n0 + NB;
    if (nend > NN) nend = NN;
    float acc = 0.f;
    int cur = -1;
    for (int n = n0; n < nend; n++) {
        int g = batch[n];
        if (g != cur) {
            if (cur >= 0) atomicAdd(&pooled[cur * 192 + sliceoff + j], acc);
            acc = 0.f;
            cur = g;
        }
        acc += src[(size_t)n * NH + j];
    }
    if (cur >= 0) atomicAdd(&pooled[cur * 192 + sliceoff + j], acc);
    if (do_gcnt && j == 0) {
        float c = 0.f;
        int cg = -1;
        for (int n = n0; n < nend; n++) {
            int g = batch[n];
            if (g != cg) {
                if (cg >= 0) atomicAdd(&gcnt[cg], c);
                c = 0.f;
                cg = g;
            }
            c += 1.f;
        }
        if (cg >= 0) atomicAdd(&gcnt[cg], c);
    }
}

// ---- head: logits = (pooled/cnt) @ Wl + bl; log_softmax; f32 out ----
__global__ __launch_bounds__(640) void k_head(const float* __restrict__ pooled,
                                              const float* __restrict__ gcnt,
                                              const float* __restrict__ Wl,
                                              const float* __restrict__ bl,
                                              float* __restrict__ out) {
    __shared__ float lg[NG][NC];
    int tid = threadIdx.x;  // 0..639
    int g = tid / NC, c = tid % NC;
    float cnt = fmaxf(gcnt[g], 1.0f);
    float acc = bl[c];
    for (int k = 0; k < 3 * NH; k++)
        acc += (pooled[g * 192 + k] / cnt) * Wl[k * NC + c];
    lg[g][c] = acc;
    __syncthreads();
    float m = -INFINITY;
#pragma unroll
    for (int q = 0; q < NC; q++) m = fmaxf(m, lg[g][q]);
    float s = 0.f;
#pragma unroll
    for (int q = 0; q < NC; q++) s += expf(lg[g][q] - m);
    out[g * NC + c] = acc - m - logf(s);
}

extern "C" void kernel_launch(void* const* d_in, const int* in_sizes, int n_in,
                              void* d_out, int out_size, void* d_ws, size_t ws_size,
                              hipStream_t stream) {
    const float* x  = (const float*)d_in[0];
    const float* W1 = (const float*)d_in[1];
    const float* b1 = (const float*)d_in[2];
    const float* W2 = (const float*)d_in[3];
    const float* b2 = (const float*)d_in[4];
    const float* W3 = (const float*)d_in[5];
    const float* b3 = (const float*)d_in[6];
    const float* W4 = (const float*)d_in[7];
    const float* b4 = (const float*)d_in[8];
    const float* Wl = (const float*)d_in[9];
    const float* bl = (const float*)d_in[10];
    const int* edge_index = (const int*)d_in[11];
    const int* batch      = (const int*)d_in[12];
    float* out = (float*)d_out;

    const size_t NP = 100032;  // NN padded to x64
    float* ws     = (float*)d_ws;
    float* dinv   = ws;                 // NP
    int*   cnt    = (int*)(ws + NP);    // NP
    float* t      = ws + 2 * NP;        // NP*64
    float* agg    = t + NP * 64;        // NP*64
    float* bufA   = agg + NP * 64;      // NP*64
    float* bufB   = bufA + NP * 64;     // NP*64
    float* pooled = bufB + NP * 64;     // 64*192
    float* gcnt   = pooled + 64 * 192;  // 64
    // total ~ 103 MB

    hipMemsetAsync(cnt, 0, NN * sizeof(int), stream);
    hipMemsetAsync(agg, 0, (size_t)NN * NH * sizeof(float), stream);
    hipMemsetAsync(pooled, 0, (64 * 192 + 64) * sizeof(float), stream);

    k_deg<<<(NE + 255) / 256, 256, 0, stream>>>(edge_index + NE, cnt);
    k_dinv<<<(NN + 255) / 256, 256, 0, stream>>>(cnt, dinv);

    const int epi_blocks = (NN * NH + 255) / 256;
    const int agg_blocks = NE / 4;  // one wave per edge, 4 waves/block
    const int pool_blocks = (NN + 127) / 128;

    // layer 1: x -> bufA; JK slice 0
    k_gemm_in<<<1024, 256, 0, stream>>>(x, W1, t);
    k_agg<<<agg_blocks, 256, 0, stream>>>(edge_index, dinv, t, agg);
    k_epi<<<epi_blocks, 256, 0, stream>>>(agg, t, dinv, b1, bufA);
    k_pool<<<pool_blocks, 64, 0, stream>>>(bufA, batch, pooled, gcnt, 0, 1);

    // layer 2: bufA -> bufB; JK slice 1
    k_gemm_h<<<1024, 256, 0, stream>>>(bufA, W2, t);
    k_agg<<<agg_blocks, 256, 0, stream>>>(edge_index, dinv, t, agg);
    k_epi<<<epi_blocks, 256, 0, stream>>>(agg, t, dinv, b2, bufB);
    k_pool<<<pool_blocks, 64, 0, stream>>>(bufB, batch, pooled, gcnt, 64, 0);

    // layer 3: bufB -> bufA (x1's buffer is free now)
    k_gemm_h<<<1024, 256, 0, stream>>>(bufB, W3, t);
    k_agg<<<agg_blocks, 256, 0, stream>>>(edge_index, dinv, t, agg);
    k_epi<<<epi_blocks, 256, 0, stream>>>(agg, t, dinv, b3, bufA);

    // layer 4: bufA -> bufB; JK slice 2 (ref overwrites x3)
    k_gemm_h<<<1024, 256, 0, stream>>>(bufA, W4, t);
    k_agg<<<agg_blocks, 256, 0, stream>>>(edge_index, dinv, t, agg);
    k_epi<<<epi_blocks, 256, 0, stream>>>(agg, t, dinv, b4, bufB);
    k_pool<<<pool_blocks, 64, 0, stream>>>(bufB, batch, pooled, gcnt, 128, 0);

    k_head<<<1, 640, 0, stream>>>(pooled, gcnt, Wl, bl, out);
}

// Round 4
// 1100.674 us; speedup vs baseline: 1.9659x; 1.9659x over previous
//
#include <hip/hip_runtime.h>

#define NN 100000
#define NE 1600000
#define NF 128
#define NH 64
#define NC 10
#define NG 64
#define NPD 100032
#define SB 512
#define NB1 ((NN + SB - 1) / SB)  // 196

// ---- degree count over dst ----
__global__ void k_deg(const int* __restrict__ dst, int* __restrict__ cnt) {
    int e = blockIdx.x * blockDim.x + threadIdx.x;
    if (e < NE) atomicAdd(&cnt[dst[e]], 1);
}

// ---- exclusive scan, phase 1: per-block scan + block sums ----
__global__ __launch_bounds__(SB) void k_scan1(const int* __restrict__ cnt,
                                              int* __restrict__ ptr,
                                              int* __restrict__ bsum) {
    __shared__ int sd[SB];
    int t = threadIdx.x;
    int i = blockIdx.x * SB + t;
    int v = (i < NN) ? cnt[i] : 0;
    sd[t] = v;
    __syncthreads();
    for (int off = 1; off < SB; off <<= 1) {
        int add = (t >= off) ? sd[t - off] : 0;
        __syncthreads();
        sd[t] += add;
        __syncthreads();
    }
    if (i < NN) ptr[i] = sd[t] - v;  // exclusive within block
    if (t == SB - 1) bsum[blockIdx.x] = sd[t];
}

// ---- phase 2: scan the 196 block sums ----
__global__ __launch_bounds__(256) void k_scan2(const int* __restrict__ bsum,
                                               int* __restrict__ bofs) {
    __shared__ int sd[256];
    int t = threadIdx.x;
    int v = (t < NB1) ? bsum[t] : 0;
    sd[t] = v;
    __syncthreads();
    for (int off = 1; off < 256; off <<= 1) {
        int add = (t >= off) ? sd[t - off] : 0;
        __syncthreads();
        sd[t] += add;
        __syncthreads();
    }
    if (t < NB1) bofs[t] = sd[t] - v;
}

// ---- phase 3: add block offsets; init write cursors + dinv ----
__global__ __launch_bounds__(SB) void k_scan3(int* __restrict__ ptr,
                                              const int* __restrict__ bofs,
                                              int* __restrict__ wptr,
                                              const int* __restrict__ cnt,
                                              float* __restrict__ dinv) {
    int i = blockIdx.x * SB + threadIdx.x;
    if (i < NN) {
        int p = ptr[i] + bofs[blockIdx.x];
        ptr[i] = p;
        wptr[i] = p;
        dinv[i] = rsqrtf((float)cnt[i] + 1.0f);  // +1 self-loop
    }
    if (i == 0) ptr[NN] = NE;
}

// ---- scatter edge srcs into CSR buckets ----
__global__ void k_scatter(const int* __restrict__ ei, int* __restrict__ wptr,
                          int* __restrict__ eid) {
    int e = blockIdx.x * blockDim.x + threadIdx.x;
    if (e < NE) {
        int d = ei[NE + e];
        int pos = atomicAdd(&wptr[d], 1);
        eid[pos] = ei[e];
    }
}

// ---- t = (h @ W) * dinv[n]; W column held in registers, h broadcast ----
template <int K>
__global__ __launch_bounds__(256) void k_gemm(const float* __restrict__ h,
                                              const float* __restrict__ W,
                                              const float* __restrict__ dinv,
                                              float* __restrict__ t) {
    int lane = threadIdx.x & 63;
    float w[K];
#pragma unroll
    for (int k = 0; k < K; k++) w[k] = W[k * NH + lane];
    int wave = (blockIdx.x * 256 + threadIdx.x) >> 6;
    int nw = (gridDim.x * 256) >> 6;
    for (int n = wave; n < NN; n += nw) {
        const float4* hv = (const float4*)(h + (size_t)n * K);
        float acc = 0.f;
#pragma unroll
        for (int q = 0; q < K / 4; q++) {
            float4 v = hv[q];
            acc = fmaf(v.x, w[4 * q + 0], acc);
            acc = fmaf(v.y, w[4 * q + 1], acc);
            acc = fmaf(v.z, w[4 * q + 2], acc);
            acc = fmaf(v.w, w[4 * q + 3], acc);
        }
        t[(size_t)n * NH + lane] = acc * dinv[n];
    }
}

// ---- pull aggregation + fused epilogue: one wave per node ----
// x[d] = relu(dinv[d] * (sum_{s in N(d)} t[s] + t[d]) + b)   (t pre-scaled by dinv)
__global__ __launch_bounds__(256) void k_pull(const int* __restrict__ ptr,
                                              const int* __restrict__ eid,
                                              const float* __restrict__ t,
                                              const float* __restrict__ dinv,
                                              const float* __restrict__ b,
                                              float* __restrict__ xout) {
    int node = (blockIdx.x * 256 + threadIdx.x) >> 6;
    int lane = threadIdx.x & 63;
    if (node >= NN) return;
    int e0 = ptr[node], e1 = ptr[node + 1];
    float acc0 = t[(size_t)node * NH + lane];  // self-loop term
    float acc1 = 0.f;
    for (int e = e0; e < e1; e += 64) {
        int m = e1 - e;
        if (m > 64) m = 64;
        int id = (lane < m) ? eid[e + lane] : 0;  // coalesced id chunk
        int j = 0;
        for (; j + 1 < m; j += 2) {
            int s0 = __shfl(id, j);
            int s1 = __shfl(id, j + 1);
            acc0 += t[(size_t)s0 * NH + lane];
            acc1 += t[(size_t)s1 * NH + lane];
        }
        if (j < m) {
            int s = __shfl(id, j);
            acc0 += t[(size_t)s * NH + lane];
        }
    }
    float val = fmaf(acc0 + acc1, dinv[node], b[lane]);
    xout[(size_t)node * NH + lane] = fmaxf(val, 0.f);
}

// ---- mean-pool slice (batch sorted): block walks NB nodes, flush per segment ----
__global__ __launch_bounds__(64) void k_pool(const float* __restrict__ src,
                                             const int* __restrict__ batch,
                                             float* __restrict__ pooled,
                                             float* __restrict__ gcnt,
                                             int sliceoff, int do_gcnt) {
    const int NB = 64;
    int j = threadIdx.x;  // 0..63
    int n0 = blockIdx.x * NB;
    int nend = n0 + NB;
    if (nend > NN) nend = NN;
    float acc = 0.f;
    int cur = -1;
    for (int n = n0; n < nend; n++) {
        int g = batch[n];
        if (g != cur) {
            if (cur >= 0) atomicAdd(&pooled[cur * 192 + sliceoff + j], acc);
            acc = 0.f;
            cur = g;
        }
        acc += src[(size_t)n * NH + j];
    }
    if (cur >= 0) atomicAdd(&pooled[cur * 192 + sliceoff + j], acc);
    if (do_gcnt && j == 0) {
        float c = 0.f;
        int cg = -1;
        for (int n = n0; n < nend; n++) {
            int g = batch[n];
            if (g != cg) {
                if (cg >= 0) atomicAdd(&gcnt[cg], c);
                c = 0.f;
                cg = g;
            }
            c += 1.f;
        }
        if (cg >= 0) atomicAdd(&gcnt[cg], c);
    }
}

// ---- head: logits = (pooled/cnt) @ Wl + bl; log_softmax; f32 out ----
__global__ __launch_bounds__(640) void k_head(const float* __restrict__ pooled,
                                              const float* __restrict__ gcnt,
                                              const float* __restrict__ Wl,
                                              const float* __restrict__ bl,
                                              float* __restrict__ out) {
    __shared__ float lg[NG][NC];
    int tid = threadIdx.x;  // 0..639
    int g = tid / NC, c = tid % NC;
    float cnt = fmaxf(gcnt[g], 1.0f);
    float acc = bl[c];
    for (int k = 0; k < 3 * NH; k++)
        acc += (pooled[g * 192 + k] / cnt) * Wl[k * NC + c];
    lg[g][c] = acc;
    __syncthreads();
    float m = -INFINITY;
#pragma unroll
    for (int q = 0; q < NC; q++) m = fmaxf(m, lg[g][q]);
    float s = 0.f;
#pragma unroll
    for (int q = 0; q < NC; q++) s += expf(lg[g][q] - m);
    out[g * NC + c] = acc - m - logf(s);
}

extern "C" void kernel_launch(void* const* d_in, const int* in_sizes, int n_in,
                              void* d_out, int out_size, void* d_ws, size_t ws_size,
                              hipStream_t stream) {
    const float* x  = (const float*)d_in[0];
    const float* W1 = (const float*)d_in[1];
    const float* b1 = (const float*)d_in[2];
    const float* W2 = (const float*)d_in[3];
    const float* b2 = (const float*)d_in[4];
    const float* W3 = (const float*)d_in[5];
    const float* b3 = (const float*)d_in[6];
    const float* W4 = (const float*)d_in[7];
    const float* b4 = (const float*)d_in[8];
    const float* Wl = (const float*)d_in[9];
    const float* bl = (const float*)d_in[10];
    const int* edge_index = (const int*)d_in[11];
    const int* batch      = (const int*)d_in[12];
    float* out = (float*)d_out;

    float* ws     = (float*)d_ws;
    float* dinv   = ws;                          // NPD
    int*   cnt    = (int*)(ws + NPD);            // NPD
    int*   ptr    = (int*)(ws + 2 * NPD);        // NPD + 64
    int*   wptr   = (int*)(ws + 3 * NPD + 64);   // NPD
    int*   bsum   = (int*)(ws + 4 * NPD + 64);   // 256
    int*   bofs   = bsum + 256;                  // 256
    int*   eid    = bofs + 256;                  // NE
    float* t      = (float*)(eid + NE);          // NPD*64
    float* bufA   = t + (size_t)NPD * 64;        // NPD*64
    float* bufB   = bufA + (size_t)NPD * 64;     // NPD*64
    float* pooled = bufB + (size_t)NPD * 64;     // 64*192
    float* gcnt   = pooled + 64 * 192;           // 64
    // total ~ 85 MB

    hipMemsetAsync(cnt, 0, NN * sizeof(int), stream);
    hipMemsetAsync(pooled, 0, (64 * 192 + 64) * sizeof(float), stream);

    // ---- CSR build (once, reused by 4 layers) ----
    k_deg<<<(NE + 255) / 256, 256, 0, stream>>>(edge_index + NE, cnt);
    k_scan1<<<NB1, SB, 0, stream>>>(cnt, ptr, bsum);
    k_scan2<<<1, 256, 0, stream>>>(bsum, bofs);
    k_scan3<<<NB1, SB, 0, stream>>>(ptr, bofs, wptr, cnt, dinv);
    k_scatter<<<(NE + 255) / 256, 256, 0, stream>>>(edge_index, wptr, eid);

    const int pull_blocks = NN / 4;  // 25000 blocks, 4 waves each, exact
    const int pool_blocks = (NN + 63) / 64;

    // layer 1: x -> bufA; JK slice 0
    k_gemm<NF><<<1024, 256, 0, stream>>>(x, W1, dinv, t);
    k_pull<<<pull_blocks, 256, 0, stream>>>(ptr, eid, t, dinv, b1, bufA);
    k_pool<<<pool_blocks, 64, 0, stream>>>(bufA, batch, pooled, gcnt, 0, 1);

    // layer 2: bufA -> bufB; JK slice 1
    k_gemm<NH><<<1024, 256, 0, stream>>>(bufA, W2, dinv, t);
    k_pull<<<pull_blocks, 256, 0, stream>>>(ptr, eid, t, dinv, b2, bufB);
    k_pool<<<pool_blocks, 64, 0, stream>>>(bufB, batch, pooled, gcnt, 64, 0);

    // layer 3: bufB -> bufA
    k_gemm<NH><<<1024, 256, 0, stream>>>(bufB, W3, dinv, t);
    k_pull<<<pull_blocks, 256, 0, stream>>>(ptr, eid, t, dinv, b3, bufA);

    // layer 4: bufA -> bufB; JK slice 2 (ref overwrites x3)
    k_gemm<NH><<<1024, 256, 0, stream>>>(bufA, W4, dinv, t);
    k_pull<<<pull_blocks, 256, 0, stream>>>(ptr, eid, t, dinv, b4, bufB);
    k_pool<<<pool_blocks, 64, 0, stream>>>(bufB, batch, pooled, gcnt, 128, 0);

    k_head<<<1, 640, 0, stream>>>(pooled, gcnt, Wl, bl, out);
}

// Round 5
// 933.676 us; speedup vs baseline: 2.3175x; 1.1789x over previous
//
#include <hip/hip_runtime.h>

#define NN 100000
#define NE 1600000
#define NF 128
#define NH 64
#define NC 10
#define NG 64
#define NPD 100032
#define SB 512
#define NB1 ((NN + SB - 1) / SB)  // 196

// ---- degree count over dst ----
__global__ void k_deg(const int* __restrict__ dst, int* __restrict__ cnt) {
    int e = blockIdx.x * blockDim.x + threadIdx.x;
    if (e < NE) atomicAdd(&cnt[dst[e]], 1);
}

// ---- exclusive scan, phase 1: per-block scan + block sums ----
__global__ __launch_bounds__(SB) void k_scan1(const int* __restrict__ cnt,
                                              int* __restrict__ ptr,
                                              int* __restrict__ bsum) {
    __shared__ int sd[SB];
    int t = threadIdx.x;
    int i = blockIdx.x * SB + t;
    int v = (i < NN) ? cnt[i] : 0;
    sd[t] = v;
    __syncthreads();
    for (int off = 1; off < SB; off <<= 1) {
        int add = (t >= off) ? sd[t - off] : 0;
        __syncthreads();
        sd[t] += add;
        __syncthreads();
    }
    if (i < NN) ptr[i] = sd[t] - v;  // exclusive within block
    if (t == SB - 1) bsum[blockIdx.x] = sd[t];
}

// ---- phase 2: scan the 196 block sums ----
__global__ __launch_bounds__(256) void k_scan2(const int* __restrict__ bsum,
                                               int* __restrict__ bofs) {
    __shared__ int sd[256];
    int t = threadIdx.x;
    int v = (t < NB1) ? bsum[t] : 0;
    sd[t] = v;
    __syncthreads();
    for (int off = 1; off < 256; off <<= 1) {
        int add = (t >= off) ? sd[t - off] : 0;
        __syncthreads();
        sd[t] += add;
        __syncthreads();
    }
    if (t < NB1) bofs[t] = sd[t] - v;
}

// ---- phase 3: add block offsets; init write cursors + dinv ----
__global__ __launch_bounds__(SB) void k_scan3(int* __restrict__ ptr,
                                              const int* __restrict__ bofs,
                                              int* __restrict__ wptr,
                                              const int* __restrict__ cnt,
                                              float* __restrict__ dinv) {
    int i = blockIdx.x * SB + threadIdx.x;
    if (i < NN) {
        int p = ptr[i] + bofs[blockIdx.x];
        ptr[i] = p;
        wptr[i] = p;
        dinv[i] = rsqrtf((float)cnt[i] + 1.0f);  // +1 self-loop
    }
    if (i == 0) ptr[NN] = NE;
}

// ---- scatter edge srcs into CSR buckets ----
__global__ void k_scatter(const int* __restrict__ ei, int* __restrict__ wptr,
                          int* __restrict__ eid) {
    int e = blockIdx.x * blockDim.x + threadIdx.x;
    if (e < NE) {
        int d = ei[NE + e];
        int pos = atomicAdd(&wptr[d], 1);
        eid[pos] = ei[e];
    }
}

// ---- t = (h @ W) * dinv[n]; W^T in LDS (padded), 4 nodes/wave iter ----
template <int K>
__global__ __launch_bounds__(256) void k_gemm(const float* __restrict__ h,
                                              const float* __restrict__ W,
                                              const float* __restrict__ dinv,
                                              float* __restrict__ t) {
    __shared__ float wT[64][K + 1];  // wT[j][k] = W[k][j]; stride K+1 -> conflict-free
    for (int idx = threadIdx.x; idx < K * 64; idx += 256) {
        int k = idx >> 6, j = idx & 63;
        wT[j][k] = W[idx];
    }
    __syncthreads();
    int lane = threadIdx.x & 63;
    int wave = (blockIdx.x * 256 + threadIdx.x) >> 6;
    int nw = (gridDim.x * 256) >> 6;
    for (int base = wave * 4; base < NN; base += nw * 4) {  // NN % 4 == 0
        const float4* h0 = (const float4*)(h + (size_t)(base + 0) * K);
        const float4* h1 = (const float4*)(h + (size_t)(base + 1) * K);
        const float4* h2 = (const float4*)(h + (size_t)(base + 2) * K);
        const float4* h3 = (const float4*)(h + (size_t)(base + 3) * K);
        float acc0 = 0.f, acc1 = 0.f, acc2 = 0.f, acc3 = 0.f;
#pragma unroll 4
        for (int q = 0; q < K / 4; q++) {
            float4 w4 = *(const float4*)&wT[lane][4 * q];
            float4 a = h0[q], b = h1[q], c = h2[q], d = h3[q];
            acc0 = fmaf(a.x, w4.x, acc0); acc0 = fmaf(a.y, w4.y, acc0);
            acc0 = fmaf(a.z, w4.z, acc0); acc0 = fmaf(a.w, w4.w, acc0);
            acc1 = fmaf(b.x, w4.x, acc1); acc1 = fmaf(b.y, w4.y, acc1);
            acc1 = fmaf(b.z, w4.z, acc1); acc1 = fmaf(b.w, w4.w, acc1);
            acc2 = fmaf(c.x, w4.x, acc2); acc2 = fmaf(c.y, w4.y, acc2);
            acc2 = fmaf(c.z, w4.z, acc2); acc2 = fmaf(c.w, w4.w, acc2);
            acc3 = fmaf(d.x, w4.x, acc3); acc3 = fmaf(d.y, w4.y, acc3);
            acc3 = fmaf(d.z, w4.z, acc3); acc3 = fmaf(d.w, w4.w, acc3);
        }
        t[(size_t)(base + 0) * NH + lane] = acc0 * dinv[base + 0];
        t[(size_t)(base + 1) * NH + lane] = acc1 * dinv[base + 1];
        t[(size_t)(base + 2) * NH + lane] = acc2 * dinv[base + 2];
        t[(size_t)(base + 3) * NH + lane] = acc3 * dinv[base + 3];
    }
}

// ---- pull aggregation + fused epilogue: one wave per node ----
// x[d] = relu(dinv[d] * (sum_{s in N(d)} t[s] + t[d]) + b)   (t pre-scaled by dinv)
__global__ __launch_bounds__(256) void k_pull(const int* __restrict__ ptr,
                                              const int* __restrict__ eid,
                                              const float* __restrict__ t,
                                              const float* __restrict__ dinv,
                                              const float* __restrict__ b,
                                              float* __restrict__ xout) {
    int node = (blockIdx.x * 256 + threadIdx.x) >> 6;
    int lane = threadIdx.x & 63;
    if (node >= NN) return;
    int e0 = ptr[node], e1 = ptr[node + 1];
    float acc0 = t[(size_t)node * NH + lane];  // self-loop term
    float acc1 = 0.f;
    for (int e = e0; e < e1; e += 64) {
        int m = e1 - e;
        if (m > 64) m = 64;
        int id = (lane < m) ? eid[e + lane] : 0;  // coalesced id chunk
        int j = 0;
        for (; j + 1 < m; j += 2) {
            int s0 = __shfl(id, j);
            int s1 = __shfl(id, j + 1);
            acc0 += t[(size_t)s0 * NH + lane];
            acc1 += t[(size_t)s1 * NH + lane];
        }
        if (j < m) {
            int s = __shfl(id, j);
            acc0 += t[(size_t)s * NH + lane];
        }
    }
    float val = fmaf(acc0 + acc1, dinv[node], b[lane]);
    xout[(size_t)node * NH + lane] = fmaxf(val, 0.f);
}

// ---- mean-pool slice (batch sorted): block walks NB nodes, flush per segment ----
__global__ __launch_bounds__(64) void k_pool(const float* __restrict__ src,
                                             const int* __restrict__ batch,
                                             float* __restrict__ pooled,
                                             float* __restrict__ gcnt,
                                             int sliceoff, int do_gcnt) {
    const int NB = 64;
    int j = threadIdx.x;  // 0..63
    int n0 = blockIdx.x * NB;
    int nend = n0 + NB;
    if (nend > NN) nend = NN;
    float acc = 0.f;
    int cur = -1;
    for (int n = n0; n < nend; n++) {
        int g = batch[n];
        if (g != cur) {
            if (cur >= 0) atomicAdd(&pooled[cur * 192 + sliceoff + j], acc);
            acc = 0.f;
            cur = g;
        }
        acc += src[(size_t)n * NH + j];
    }
    if (cur >= 0) atomicAdd(&pooled[cur * 192 + sliceoff + j], acc);
    if (do_gcnt && j == 0) {
        float c = 0.f;
        int cg = -1;
        for (int n = n0; n < nend; n++) {
            int g = batch[n];
            if (g != cg) {
                if (cg >= 0) atomicAdd(&gcnt[cg], c);
                c = 0.f;
                cg = g;
            }
            c += 1.f;
        }
        if (cg >= 0) atomicAdd(&gcnt[cg], c);
    }
}

// ---- head: logits = (pooled/cnt) @ Wl + bl; log_softmax; f32 out ----
__global__ __launch_bounds__(640) void k_head(const float* __restrict__ pooled,
                                              const float* __restrict__ gcnt,
                                              const float* __restrict__ Wl,
                                              const float* __restrict__ bl,
                                              float* __restrict__ out) {
    __shared__ float lg[NG][NC];
    int tid = threadIdx.x;  // 0..639
    int g = tid / NC, c = tid % NC;
    float cnt = fmaxf(gcnt[g], 1.0f);
    float acc = bl[c];
    for (int k = 0; k < 3 * NH; k++)
        acc += (pooled[g * 192 + k] / cnt) * Wl[k * NC + c];
    lg[g][c] = acc;
    __syncthreads();
    float m = -INFINITY;
#pragma unroll
    for (int q = 0; q < NC; q++) m = fmaxf(m, lg[g][q]);
    float s = 0.f;
#pragma unroll
    for (int q = 0; q < NC; q++) s += expf(lg[g][q] - m);
    out[g * NC + c] = acc - m - logf(s);
}

extern "C" void kernel_launch(void* const* d_in, const int* in_sizes, int n_in,
                              void* d_out, int out_size, void* d_ws, size_t ws_size,
                              hipStream_t stream) {
    const float* x  = (const float*)d_in[0];
    const float* W1 = (const float*)d_in[1];
    const float* b1 = (const float*)d_in[2];
    const float* W2 = (const float*)d_in[3];
    const float* b2 = (const float*)d_in[4];
    const float* W3 = (const float*)d_in[5];
    const float* b3 = (const float*)d_in[6];
    const float* W4 = (const float*)d_in[7];
    const float* b4 = (const float*)d_in[8];
    const float* Wl = (const float*)d_in[9];
    const float* bl = (const float*)d_in[10];
    const int* edge_index = (const int*)d_in[11];
    const int* batch      = (const int*)d_in[12];
    float* out = (float*)d_out;

    float* ws     = (float*)d_ws;
    float* dinv   = ws;                          // NPD
    int*   cnt    = (int*)(ws + NPD);            // NPD
    int*   ptr    = (int*)(ws + 2 * NPD);        // NPD + 64
    int*   wptr   = (int*)(ws + 3 * NPD + 64);   // NPD
    int*   bsum   = (int*)(ws + 4 * NPD + 64);   // 256
    int*   bofs   = bsum + 256;                  // 256
    int*   eid    = bofs + 256;                  // NE
    float* t      = (float*)(eid + NE);          // NPD*64
    float* bufA   = t + (size_t)NPD * 64;        // NPD*64
    float* bufB   = bufA + (size_t)NPD * 64;     // NPD*64
    float* pooled = bufB + (size_t)NPD * 64;     // 64*192
    float* gcnt   = pooled + 64 * 192;           // 64
    // total ~ 85 MB

    hipMemsetAsync(cnt, 0, NN * sizeof(int), stream);
    hipMemsetAsync(pooled, 0, (64 * 192 + 64) * sizeof(float), stream);

    // ---- CSR build (once, reused by 4 layers) ----
    k_deg<<<(NE + 255) / 256, 256, 0, stream>>>(edge_index + NE, cnt);
    k_scan1<<<NB1, SB, 0, stream>>>(cnt, ptr, bsum);
    k_scan2<<<1, 256, 0, stream>>>(bsum, bofs);
    k_scan3<<<NB1, SB, 0, stream>>>(ptr, bofs, wptr, cnt, dinv);
    k_scatter<<<(NE + 255) / 256, 256, 0, stream>>>(edge_index, wptr, eid);

    const int pull_blocks = NN / 4;  // 25000 blocks, 4 waves each, exact
    const int pool_blocks = (NN + 63) / 64;

    // layer 1: x -> bufA; JK slice 0
    k_gemm<NF><<<1024, 256, 0, stream>>>(x, W1, dinv, t);
    k_pull<<<pull_blocks, 256, 0, stream>>>(ptr, eid, t, dinv, b1, bufA);
    k_pool<<<pool_blocks, 64, 0, stream>>>(bufA, batch, pooled, gcnt, 0, 1);

    // layer 2: bufA -> bufB; JK slice 1
    k_gemm<NH><<<1024, 256, 0, stream>>>(bufA, W2, dinv, t);
    k_pull<<<pull_blocks, 256, 0, stream>>>(ptr, eid, t, dinv, b2, bufB);
    k_pool<<<pool_blocks, 64, 0, stream>>>(bufB, batch, pooled, gcnt, 64, 0);

    // layer 3: bufB -> bufA
    k_gemm<NH><<<1024, 256, 0, stream>>>(bufB, W3, dinv, t);
    k_pull<<<pull_blocks, 256, 0, stream>>>(ptr, eid, t, dinv, b3, bufA);

    // layer 4: bufA -> bufB; JK slice 2 (ref overwrites x3)
    k_gemm<NH><<<1024, 256, 0, stream>>>(bufA, W4, dinv, t);
    k_pull<<<pull_blocks, 256, 0, stream>>>(ptr, eid, t, dinv, b4, bufB);
    k_pool<<<pool_blocks, 64, 0, stream>>>(bufB, batch, pooled, gcnt, 128, 0);

    k_head<<<1, 640, 0, stream>>>(pooled, gcnt, Wl, bl, out);
}

// Round 6
// 876.780 us; speedup vs baseline: 2.4679x; 1.0649x over previous
//
#include <hip/hip_runtime.h>

#define NN 100000
#define NE 1600000
#define NF 128
#define NH 64
#define NC 10
#define NG 64
#define NPD 100032
#define SB 512
#define NB1 ((NN + SB - 1) / SB)  // 196
#define RNODES 12500              // nodes per dst-range (8 ranges)
#define NSLICE 64                 // edge slices for range-filtered passes
#define EPERS (NE / NSLICE)       // 25000 edges per slice

// ---- degree count over dst, range-filtered for XCD-local atomics ----
__global__ __launch_bounds__(256) void k_deg(const int* __restrict__ dst,
                                             int* __restrict__ cnt) {
    int r = blockIdx.x & 7;        // dst range (heuristic: same XCD for same r)
    int slice = blockIdx.x >> 3;   // edge slice
    int lo = r * RNODES, hi = lo + RNODES;
    int e0 = slice * EPERS;
    for (int e = e0 + threadIdx.x; e < e0 + EPERS; e += 256) {
        int d = dst[e];
        if (d >= lo && d < hi) atomicAdd(&cnt[d], 1);
    }
}

// ---- exclusive scan, phase 1: per-block scan + block sums ----
__global__ __launch_bounds__(SB) void k_scan1(const int* __restrict__ cnt,
                                              int* __restrict__ ptr,
                                              int* __restrict__ bsum) {
    __shared__ int sd[SB];
    int t = threadIdx.x;
    int i = blockIdx.x * SB + t;
    int v = (i < NN) ? cnt[i] : 0;
    sd[t] = v;
    __syncthreads();
    for (int off = 1; off < SB; off <<= 1) {
        int add = (t >= off) ? sd[t - off] : 0;
        __syncthreads();
        sd[t] += add;
        __syncthreads();
    }
    if (i < NN) ptr[i] = sd[t] - v;  // exclusive within block
    if (t == SB - 1) bsum[blockIdx.x] = sd[t];
}

// ---- phase 2: scan the 196 block sums ----
__global__ __launch_bounds__(256) void k_scan2(const int* __restrict__ bsum,
                                               int* __restrict__ bofs) {
    __shared__ int sd[256];
    int t = threadIdx.x;
    int v = (t < NB1) ? bsum[t] : 0;
    sd[t] = v;
    __syncthreads();
    for (int off = 1; off < 256; off <<= 1) {
        int add = (t >= off) ? sd[t - off] : 0;
        __syncthreads();
        sd[t] += add;
        __syncthreads();
    }
    if (t < NB1) bofs[t] = sd[t] - v;
}

// ---- phase 3: add block offsets; init write cursors + dinv ----
__global__ __launch_bounds__(SB) void k_scan3(int* __restrict__ ptr,
                                              const int* __restrict__ bofs,
                                              int* __restrict__ wptr,
                                              const int* __restrict__ cnt,
                                              float* __restrict__ dinv) {
    int i = blockIdx.x * SB + threadIdx.x;
    if (i < NN) {
        int p = ptr[i] + bofs[blockIdx.x];
        ptr[i] = p;
        wptr[i] = p;
        dinv[i] = rsqrtf((float)cnt[i] + 1.0f);  // +1 self-loop
    }
    if (i == 0) ptr[NN] = NE;
}

// ---- scatter edge srcs into CSR buckets, range-filtered (L2-local writes) ----
__global__ __launch_bounds__(256) void k_scatter(const int* __restrict__ ei,
                                                 int* __restrict__ wptr,
                                                 int* __restrict__ eid) {
    int r = blockIdx.x & 7;
    int slice = blockIdx.x >> 3;
    int lo = r * RNODES, hi = lo + RNODES;
    int e0 = slice * EPERS;
    for (int e = e0 + threadIdx.x; e < e0 + EPERS; e += 256) {
        int d = ei[NE + e];
        if (d >= lo && d < hi) {
            int pos = atomicAdd(&wptr[d], 1);
            eid[pos] = ei[e];
        }
    }
}

// ---- t = (h @ W) * dinv[n]; W^T in LDS (padded), 4 nodes/wave iter ----
template <int K>
__global__ __launch_bounds__(256) void k_gemm(const float* __restrict__ h,
                                              const float* __restrict__ W,
                                              const float* __restrict__ dinv,
                                              float* __restrict__ t) {
    __shared__ float wT[64][K + 1];  // wT[j][k] = W[k][j]; stride K+1 -> conflict-free
    for (int idx = threadIdx.x; idx < K * 64; idx += 256) {
        int k = idx >> 6, j = idx & 63;
        wT[j][k] = W[idx];
    }
    __syncthreads();
    int lane = threadIdx.x & 63;
    int wave = (blockIdx.x * 256 + threadIdx.x) >> 6;
    int nw = (gridDim.x * 256) >> 6;
    for (int base = wave * 4; base < NN; base += nw * 4) {  // NN % 4 == 0
        const float4* h0 = (const float4*)(h + (size_t)(base + 0) * K);
        const float4* h1 = (const float4*)(h + (size_t)(base + 1) * K);
        const float4* h2 = (const float4*)(h + (size_t)(base + 2) * K);
        const float4* h3 = (const float4*)(h + (size_t)(base + 3) * K);
        float acc0 = 0.f, acc1 = 0.f, acc2 = 0.f, acc3 = 0.f;
#pragma unroll 4
        for (int q = 0; q < K / 4; q++) {
            float4 w4 = *(const float4*)&wT[lane][4 * q];
            float4 a = h0[q], b = h1[q], c = h2[q], d = h3[q];
            acc0 = fmaf(a.x, w4.x, acc0); acc0 = fmaf(a.y, w4.y, acc0);
            acc0 = fmaf(a.z, w4.z, acc0); acc0 = fmaf(a.w, w4.w, acc0);
            acc1 = fmaf(b.x, w4.x, acc1); acc1 = fmaf(b.y, w4.y, acc1);
            acc1 = fmaf(b.z, w4.z, acc1); acc1 = fmaf(b.w, w4.w, acc1);
            acc2 = fmaf(c.x, w4.x, acc2); acc2 = fmaf(c.y, w4.y, acc2);
            acc2 = fmaf(c.z, w4.z, acc2); acc2 = fmaf(c.w, w4.w, acc2);
            acc3 = fmaf(d.x, w4.x, acc3); acc3 = fmaf(d.y, w4.y, acc3);
            acc3 = fmaf(d.z, w4.z, acc3); acc3 = fmaf(d.w, w4.w, acc3);
        }
        t[(size_t)(base + 0) * NH + lane] = acc0 * dinv[base + 0];
        t[(size_t)(base + 1) * NH + lane] = acc1 * dinv[base + 1];
        t[(size_t)(base + 2) * NH + lane] = acc2 * dinv[base + 2];
        t[(size_t)(base + 3) * NH + lane] = acc3 * dinv[base + 3];
    }
}

// ---- pull aggregation + fused epilogue: one wave per node, 4 gather chains ----
// x[d] = relu(dinv[d] * (sum_{s in N(d)} t[s] + t[d]) + b)   (t pre-scaled by dinv)
__global__ __launch_bounds__(256) void k_pull(const int* __restrict__ ptr,
                                              const int* __restrict__ eid,
                                              const float* __restrict__ t,
                                              const float* __restrict__ dinv,
                                              const float* __restrict__ b,
                                              float* __restrict__ xout) {
    int node = (blockIdx.x * 256 + threadIdx.x) >> 6;
    int lane = threadIdx.x & 63;
    if (node >= NN) return;
    int e0 = ptr[node], e1 = ptr[node + 1];
    float acc0 = t[(size_t)node * NH + lane];  // self-loop term
    float acc1 = 0.f, acc2 = 0.f, acc3 = 0.f;
    for (int e = e0; e < e1; e += 64) {
        int m = e1 - e;
        if (m > 64) m = 64;
        int id = (lane < m) ? eid[e + lane] : 0;  // coalesced id chunk
        int j = 0;
        for (; j + 3 < m; j += 4) {
            int s0 = __shfl(id, j);
            int s1 = __shfl(id, j + 1);
            int s2 = __shfl(id, j + 2);
            int s3 = __shfl(id, j + 3);
            acc0 += t[(size_t)s0 * NH + lane];
            acc1 += t[(size_t)s1 * NH + lane];
            acc2 += t[(size_t)s2 * NH + lane];
            acc3 += t[(size_t)s3 * NH + lane];
        }
        for (; j < m; j++) {
            int s = __shfl(id, j);
            acc0 += t[(size_t)s * NH + lane];
        }
    }
    float val = fmaf((acc0 + acc1) + (acc2 + acc3), dinv[node], b[lane]);
    xout[(size_t)node * NH + lane] = fmaxf(val, 0.f);
}

// ---- mean-pool slice (batch sorted): 4 waves/block, 16 nodes per wave ----
__global__ __launch_bounds__(256) void k_pool(const float* __restrict__ src,
                                              const int* __restrict__ batch,
                                              float* __restrict__ pooled,
                                              float* __restrict__ gcnt,
                                              int sliceoff, int do_gcnt) {
    int wv = threadIdx.x >> 6;
    int lane = threadIdx.x & 63;
    int n0 = blockIdx.x * 64 + wv * 16;
    int nend = n0 + 16;
    if (nend > NN) nend = NN;
    if (n0 >= NN) return;
    float acc = 0.f;
    int cur = -1;
    for (int n = n0; n < nend; n++) {
        int g = batch[n];
        if (g != cur) {
            if (cur >= 0) atomicAdd(&pooled[cur * 192 + sliceoff + lane], acc);
            acc = 0.f;
            cur = g;
        }
        acc += src[(size_t)n * NH + lane];
    }
    if (cur >= 0) atomicAdd(&pooled[cur * 192 + sliceoff + lane], acc);
    if (do_gcnt && lane == 0) {
        float c = 0.f;
        int cg = -1;
        for (int n = n0; n < nend; n++) {
            int g = batch[n];
            if (g != cg) {
                if (cg >= 0) atomicAdd(&gcnt[cg], c);
                c = 0.f;
                cg = g;
            }
            c += 1.f;
        }
        if (cg >= 0) atomicAdd(&gcnt[cg], c);
    }
}

// ---- head: logits = (pooled/cnt) @ Wl + bl; log_softmax; f32 out ----
__global__ __launch_bounds__(640) void k_head(const float* __restrict__ pooled,
                                              const float* __restrict__ gcnt,
                                              const float* __restrict__ Wl,
                                              const float* __restrict__ bl,
                                              float* __restrict__ out) {
    __shared__ float lg[NG][NC];
    int tid = threadIdx.x;  // 0..639
    int g = tid / NC, c = tid % NC;
    float cnt = fmaxf(gcnt[g], 1.0f);
    float acc = bl[c];
    for (int k = 0; k < 3 * NH; k++)
        acc += (pooled[g * 192 + k] / cnt) * Wl[k * NC + c];
    lg[g][c] = acc;
    __syncthreads();
    float m = -INFINITY;
#pragma unroll
    for (int q = 0; q < NC; q++) m = fmaxf(m, lg[g][q]);
    float s = 0.f;
#pragma unroll
    for (int q = 0; q < NC; q++) s += expf(lg[g][q] - m);
    out[g * NC + c] = acc - m - logf(s);
}

extern "C" void kernel_launch(void* const* d_in, const int* in_sizes, int n_in,
                              void* d_out, int out_size, void* d_ws, size_t ws_size,
                              hipStream_t stream) {
    const float* x  = (const float*)d_in[0];
    const float* W1 = (const float*)d_in[1];
    const float* b1 = (const float*)d_in[2];
    const float* W2 = (const float*)d_in[3];
    const float* b2 = (const float*)d_in[4];
    const float* W3 = (const float*)d_in[5];
    const float* b3 = (const float*)d_in[6];
    const float* W4 = (const float*)d_in[7];
    const float* b4 = (const float*)d_in[8];
    const float* Wl = (const float*)d_in[9];
    const float* bl = (const float*)d_in[10];
    const int* edge_index = (const int*)d_in[11];
    const int* batch      = (const int*)d_in[12];
    float* out = (float*)d_out;

    float* ws     = (float*)d_ws;
    float* dinv   = ws;                          // NPD
    int*   cnt    = (int*)(ws + NPD);            // NPD
    int*   ptr    = (int*)(ws + 2 * NPD);        // NPD + 64
    int*   wptr   = (int*)(ws + 3 * NPD + 64);   // NPD
    int*   bsum   = (int*)(ws + 4 * NPD + 64);   // 256
    int*   bofs   = bsum + 256;                  // 256
    int*   eid    = bofs + 256;                  // NE
    float* t      = (float*)(eid + NE);          // NPD*64
    float* bufA   = t + (size_t)NPD * 64;        // NPD*64
    float* bufB   = bufA + (size_t)NPD * 64;     // NPD*64
    float* pooled = bufB + (size_t)NPD * 64;     // 64*192
    float* gcnt   = pooled + 64 * 192;           // 64
    // total ~ 85 MB

    hipMemsetAsync(cnt, 0, NN * sizeof(int), stream);
    hipMemsetAsync(pooled, 0, (64 * 192 + 64) * sizeof(float), stream);

    // ---- CSR build (once, reused by 4 layers) ----
    k_deg<<<NSLICE * 8, 256, 0, stream>>>(edge_index + NE, cnt);
    k_scan1<<<NB1, SB, 0, stream>>>(cnt, ptr, bsum);
    k_scan2<<<1, 256, 0, stream>>>(bsum, bofs);
    k_scan3<<<NB1, SB, 0, stream>>>(ptr, bofs, wptr, cnt, dinv);
    k_scatter<<<NSLICE * 8, 256, 0, stream>>>(edge_index, wptr, eid);

    const int pull_blocks = NN / 4;  // 25000 blocks, 4 waves each, exact
    const int pool_blocks = (NN + 63) / 64;

    // layer 1: x -> bufA; JK slice 0
    k_gemm<NF><<<1024, 256, 0, stream>>>(x, W1, dinv, t);
    k_pull<<<pull_blocks, 256, 0, stream>>>(ptr, eid, t, dinv, b1, bufA);
    k_pool<<<pool_blocks, 256, 0, stream>>>(bufA, batch, pooled, gcnt, 0, 1);

    // layer 2: bufA -> bufB; JK slice 1
    k_gemm<NH><<<1024, 256, 0, stream>>>(bufA, W2, dinv, t);
    k_pull<<<pull_blocks, 256, 0, stream>>>(ptr, eid, t, dinv, b2, bufB);
    k_pool<<<pool_blocks, 256, 0, stream>>>(bufB, batch, pooled, gcnt, 64, 0);

    // layer 3: bufB -> bufA
    k_gemm<NH><<<1024, 256, 0, stream>>>(bufB, W3, dinv, t);
    k_pull<<<pull_blocks, 256, 0, stream>>>(ptr, eid, t, dinv, b3, bufA);

    // layer 4: bufA -> bufB; JK slice 2 (ref overwrites x3)
    k_gemm<NH><<<1024, 256, 0, stream>>>(bufA, W4, dinv, t);
    k_pull<<<pull_blocks, 256, 0, stream>>>(ptr, eid, t, dinv, b4, bufB);
    k_pool<<<pool_blocks, 256, 0, stream>>>(bufB, batch, pooled, gcnt, 128, 0);

    k_head<<<1, 640, 0, stream>>>(pooled, gcnt, Wl, bl, out);
}